// Round 7
// baseline (735.918 us; speedup 1.0000x reference)
//
#include <hip/hip_runtime.h>
#include <hip/hip_bf16.h>
#include <math.h>

#define NB 16       // B
#define NL 32       // L
#define NH 768      // H
#define NE 200000   // E
#define NR 512      // R
#define NT 2000000  // T
#define FEPS 1e-6f

#define EB_BLOCKS ((NE + 255) / 256)   // 782
#define NT_BLOCKS ((NT + 255) / 256)   // 7813

typedef float f32x4 __attribute__((ext_vector_type(4)));

// ---------------------------------------------------------------------------
// K0: transpose heads (B,E) -> headsT (E,B).  Coalesced both sides via LDS.
// ---------------------------------------------------------------------------
__global__ __launch_bounds__(256) void k_transpose(const float* __restrict__ heads,
                                                   float* __restrict__ headsT) {
  __shared__ float tile[256][17];
  int e0 = blockIdx.x * 256;
  int tid = threadIdx.x;
  if (e0 + tid < NE) {
#pragma unroll
    for (int b = 0; b < NB; ++b)
      tile[tid][b] = heads[(size_t)b * NE + e0 + tid];
  }
  __syncthreads();
#pragma unroll
  for (int j = 0; j < 16; ++j) {
    int idx = j * 256 + tid;      // 0..4095 over (i,b)
    int i = idx >> 4, b = idx & 15;
    if (e0 + i < NE) headsT[(size_t)(e0 + i) * NB + b] = tile[i][b];
  }
}

// ---------------------------------------------------------------------------
// K1: dual row-MM (measured in round-6 baseline).  Blocks < nblk0 compute
// Y0 = act0(X0 @ W0 + b0); blocks >= nblk0 compute Y1 = act1(X1 @ W1 + b1).
// 2 rows per block, 256 threads, thread owns h = {tid, tid+256, tid+512}.
// ---------------------------------------------------------------------------
__global__ __launch_bounds__(256) void k_rowmm2(const float* __restrict__ X0,
                                                const float* __restrict__ W0,
                                                const float* __restrict__ b0,
                                                float* __restrict__ Y0, int act0,
                                                const float* __restrict__ X1,
                                                const float* __restrict__ W1,
                                                const float* __restrict__ b1,
                                                float* __restrict__ Y1, int act1,
                                                int nblk0) {
  const float* X; const float* W; const float* bias; float* Y; int act, row0;
  int blk = blockIdx.x;
  if (blk < nblk0) { X = X0; W = W0; bias = b0; Y = Y0; act = act0; row0 = blk * 2; }
  else            { X = X1; W = W1; bias = b1; Y = Y1; act = act1; row0 = (blk - nblk0) * 2; }

  __shared__ float xs[2][NH];
  int tid = threadIdx.x;
  for (int r = 0; r < 2; ++r)
    for (int k = tid; k < NH; k += 256)
      xs[r][k] = X[(size_t)(row0 + r) * NH + k];
  __syncthreads();

  float acc[2][3] = {};
  for (int k = 0; k < NH; ++k) {
    float w0 = W[(size_t)k * NH + tid];
    float w1 = W[(size_t)k * NH + tid + 256];
    float w2 = W[(size_t)k * NH + tid + 512];
#pragma unroll
    for (int r = 0; r < 2; ++r) {
      float x = xs[r][k];
      acc[r][0] = fmaf(x, w0, acc[r][0]);
      acc[r][1] = fmaf(x, w1, acc[r][1]);
      acc[r][2] = fmaf(x, w2, acc[r][2]);
    }
  }
  float bb0 = bias[tid], bb1 = bias[tid + 256], bb2 = bias[tid + 512];
#pragma unroll
  for (int r = 0; r < 2; ++r) {
    size_t base = (size_t)(row0 + r) * NH;
    float y0 = acc[r][0] + bb0, y1 = acc[r][1] + bb1, y2 = acc[r][2] + bb2;
    if (act == 1) {
      y0 = 1.f / (1.f + expf(-y0));
      y1 = 1.f / (1.f + expf(-y1));
      y2 = 1.f / (1.f + expf(-y2));
    }
    Y[base + tid] = y0;
    Y[base + tid + 256] = y1;
    Y[base + tid + 512] = y2;
  }
}

// ---------------------------------------------------------------------------
// K2: per b: q_logits = qwh @ h_key^T (L,L); softmax(ax=2)*mask, renorm;
//     colsum over i; att = softmax(colsum)*mask, renorm.  (round-6 measured)
// ---------------------------------------------------------------------------
__global__ __launch_bounds__(1024) void k_attn(const float* __restrict__ qwh,
                                               const float* __restrict__ hkey,
                                               const float* __restrict__ mask,
                                               float* __restrict__ q_dist,
                                               float* __restrict__ att) {
  int b = blockIdx.x;
  int tid = threadIdx.x;
  int i = tid >> 5, j = tid & 31;
  __shared__ float hks[32 * 129];
  __shared__ float qs[32 * 129];
  __shared__ float qd[32 * 33];

  float acc = 0.f;
  for (int k0 = 0; k0 < NH; k0 += 128) {
    __syncthreads();
    {
      int jj = tid >> 5;      // row 0..31
      int kk4 = tid & 31;     // float4 index 0..31
      size_t goff = ((size_t)b * NL + jj) * NH + k0 + kk4 * 4;
      f32x4 hv = *(const f32x4*)(hkey + goff);
      f32x4 qv = *(const f32x4*)(qwh + goff);
      int base = jj * 129 + kk4 * 4;
      hks[base] = hv.x; hks[base + 1] = hv.y; hks[base + 2] = hv.z; hks[base + 3] = hv.w;
      qs[base] = qv.x;  qs[base + 1] = qv.y;  qs[base + 2] = qv.z;  qs[base + 3] = qv.w;
    }
    __syncthreads();
#pragma unroll 8
    for (int kk = 0; kk < 128; ++kk)
      acc = fmaf(qs[i * 129 + kk], hks[j * 129 + kk], acc);
  }

  float m = acc;
  for (int s = 16; s; s >>= 1) m = fmaxf(m, __shfl_xor(m, s, 32));
  float ex = expf(acc - m);
  float sum = ex;
  for (int s = 16; s; s >>= 1) sum += __shfl_xor(sum, s, 32);
  float p = ex / sum;
  p *= mask[b * NL + j];
  float s2 = p;
  for (int s = 16; s; s >>= 1) s2 += __shfl_xor(s2, s, 32);
  p = p / (s2 + FEPS);

  q_dist[((size_t)b * NL + i) * NL + j] = p;
  qd[i * 33 + j] = p;
  __syncthreads();

  if (tid < 32) {
    int jj = tid;
    float c = 0.f;
    for (int ii = 0; ii < 32; ++ii) c += qd[ii * 33 + jj];
    float mm = c;
    for (int s = 16; s; s >>= 1) mm = fmaxf(mm, __shfl_xor(mm, s, 32));
    float e2 = expf(c - mm);
    float ss = e2;
    for (int s = 16; s; s >>= 1) ss += __shfl_xor(ss, s, 32);
    float a = e2 / ss;
    a *= mask[b * NL + jj];
    float s3 = a;
    for (int s = 16; s; s >>= 1) s3 += __shfl_xor(s3, s, 32);
    a = a / (s3 + FEPS);
    att[b * NL + jj] = a;
  }
}

// ---------------------------------------------------------------------------
// K3: fused per-b update + rel projection.  (round-6 measured)
// ---------------------------------------------------------------------------
template <int STEP>
__global__ __launch_bounds__(256) void k_update_rel(const float* __restrict__ qwh,
                                                    const float* __restrict__ qhop_old,
                                                    const float* __restrict__ q_dist,
                                                    const float* __restrict__ att,
                                                    const float* __restrict__ zbuf,
                                                    const float* __restrict__ pc_old,
                                                    float* __restrict__ qhop_new,
                                                    float* __restrict__ pc_new,
                                                    float* __restrict__ ctx_h,
                                                    const float* __restrict__ rel_w,
                                                    const float* __restrict__ rel_b,
                                                    float* __restrict__ relT) {
  int b = blockIdx.x;
  int tid = threadIdx.x;
  __shared__ float qd[NL * NL];
  __shared__ float as[NL];
  __shared__ float ctx_s[NH];
  for (int idx = tid; idx < NL * NL; idx += 256) qd[idx] = q_dist[(size_t)b * NL * NL + idx];
  if (tid < NL) as[tid] = att[b * NL + tid];
  __syncthreads();

  float qh0[NL], qh1[NL], qh2[NL];
#pragma unroll
  for (int j = 0; j < NL; ++j) {
    const float* p = qhop_old + ((size_t)b * NL + j) * NH + tid;
    qh0[j] = p[0];
    qh1[j] = p[256];
    qh2[j] = p[512];
  }

  float c0 = 0.f, c1 = 0.f, c2 = 0.f;
  for (int l = 0; l < NL; ++l) {
    float h0 = 0.f, h1 = 0.f, h2 = 0.f;
#pragma unroll
    for (int j = 0; j < NL; ++j) {
      float d = qd[l * NL + j];
      h0 = fmaf(d, qh0[j], h0);
      h1 = fmaf(d, qh1[j], h1);
      h2 = fmaf(d, qh2[j], h2);
    }
    size_t base = ((size_t)b * NL + l) * NH + tid;
    float qn0, qn1, qn2;
    if (STEP == 0) {
      qn0 = qwh[base] + h0;
      qn1 = qwh[base + 256] + h1;
      qn2 = qwh[base + 512] + h2;
      qhop_new[base] = qn0;
      qhop_new[base + 256] = qn1;
      qhop_new[base + 512] = qn2;
      pc_new[base] = h0;
      pc_new[base + 256] = h1;
      pc_new[base + 512] = h2;
    } else {
      float t0 = zbuf[base] * pc_old[base];
      float t1 = zbuf[base + 256] * pc_old[base + 256];
      float t2 = zbuf[base + 512] * pc_old[base + 512];
      qn0 = qwh[base] + h0 + t0;
      qn1 = qwh[base + 256] + h1 + t1;
      qn2 = qwh[base + 512] + h2 + t2;
    }
    float a = as[l];
    c0 = fmaf(a, qn0, c0);
    c1 = fmaf(a, qn1, c1);
    c2 = fmaf(a, qn2, c2);
  }
  size_t cb = ((size_t)b * 2 + STEP) * NH + tid;
  ctx_h[cb] = c0;
  ctx_h[cb + 256] = c1;
  ctx_h[cb + 512] = c2;
  ctx_s[tid] = c0;
  ctx_s[tid + 256] = c1;
  ctx_s[tid + 512] = c2;
  __syncthreads();

  float accA = rel_b[tid], accB = rel_b[tid + 256];
  for (int h = 0; h < NH; ++h) {
    float c = ctx_s[h];  // LDS broadcast
    accA = fmaf(c, rel_w[(size_t)h * NR + tid], accA);
    accB = fmaf(c, rel_w[(size_t)h * NR + tid + 256], accB);
  }
  relT[tid * NB + b] = 1.f / (1.f + expf(-accA));
  relT[(tid + 256) * NB + b] = 1.f / (1.f + expf(-accB));
}

// ---------------------------------------------------------------------------
// CSR build: deg histogram -> two-level exclusive scan -> fill.
// obj is uniform random over 200K -> in-degree ~ Poisson(10), balanced.
// ---------------------------------------------------------------------------
__global__ __launch_bounds__(256) void k_hist(const int* __restrict__ obj,
                                              int* __restrict__ deg) {
  int k = blockIdx.x * 256 + threadIdx.x;
  if (k < NT) atomicAdd(&deg[obj[k]], 1);
}

__global__ __launch_bounds__(256) void k_scan1(const int* __restrict__ deg,
                                               int* __restrict__ bsum) {
  int e = blockIdx.x * 256 + threadIdx.x;
  int v = (e < NE) ? deg[e] : 0;
#pragma unroll
  for (int s = 32; s; s >>= 1) v += __shfl_down(v, s, 64);
  __shared__ int wsum[4];
  if ((threadIdx.x & 63) == 0) wsum[threadIdx.x >> 6] = v;
  __syncthreads();
  if (threadIdx.x == 0) bsum[blockIdx.x] = wsum[0] + wsum[1] + wsum[2] + wsum[3];
}

__global__ __launch_bounds__(1024) void k_scan2(const int* __restrict__ bsum,
                                                int* __restrict__ bbase,
                                                int* __restrict__ off) {
  __shared__ int s[1024];
  int t = threadIdx.x;
  int v = (t < EB_BLOCKS) ? bsum[t] : 0;
  s[t] = v;
  __syncthreads();
  for (int d = 1; d < 1024; d <<= 1) {
    int x = (t >= d) ? s[t - d] : 0;
    __syncthreads();
    s[t] += x;
    __syncthreads();
  }
  if (t < EB_BLOCKS) bbase[t] = s[t] - v;  // exclusive
  if (t == 0) off[NE] = NT;
}

__global__ __launch_bounds__(256) void k_scan3(const int* __restrict__ deg,
                                               const int* __restrict__ bbase,
                                               int* __restrict__ off,
                                               int* __restrict__ cursor) {
  __shared__ int s[256];
  int t = threadIdx.x;
  int e = blockIdx.x * 256 + t;
  int v = (e < NE) ? deg[e] : 0;
  s[t] = v;
  __syncthreads();
  for (int d = 1; d < 256; d <<= 1) {
    int x = (t >= d) ? s[t - d] : 0;
    __syncthreads();
    s[t] += x;
    __syncthreads();
  }
  if (e < NE) {
    int o = bbase[blockIdx.x] + s[t] - v;  // exclusive
    off[e] = o;
    cursor[e] = o;
  }
}

__global__ __launch_bounds__(256) void k_fill(const int* __restrict__ subj,
                                              const int* __restrict__ rel,
                                              const int* __restrict__ obj,
                                              int* __restrict__ cursor,
                                              int2* __restrict__ csr) {
  int k = blockIdx.x * 256 + threadIdx.x;
  if (k < NT) {
    int o = obj[k];
    int pos = atomicAdd(&cursor[o], 1);
    csr[pos] = make_int2(subj[k], rel[k]);
  }
}

// ---------------------------------------------------------------------------
// K5-CSR: atomic-free follow.  One 16-lane group per entity e; lane b owns
// batch b.  All lanes of a group read the same csr entry (broadcast) and one
// 64B line each for gather / relT; single coalesced write, no memset needed.
// CLAMP fuses prev-step z_norm: min(x,1).
// ---------------------------------------------------------------------------
template <int CLAMP>
__global__ __launch_bounds__(256) void k_follow_csr(const int* __restrict__ off,
                                                    const int2* __restrict__ csr,
                                                    const float* __restrict__ srcT,
                                                    const float* __restrict__ relT,
                                                    float* __restrict__ dstT) {
  int e = blockIdx.x * 16 + (threadIdx.x >> 4);   // 12500 blocks * 16 = NE exact
  int b = threadIdx.x & 15;
  int i0 = off[e], i1 = off[e + 1];
  float acc = 0.f;
  for (int idx = i0; idx < i1; ++idx) {
    int2 sr = csr[idx];
    float x = srcT[(size_t)sr.x * NB + b];
    if (CLAMP) x = fminf(x, 1.f);
    acc = fmaf(x, relT[sr.y * NB + b], acc);
  }
  dstT[(size_t)e * NB + b] = acc;
}

// ---------------------------------------------------------------------------
// K5 fallback (measured round-1/6 form, 113us) — used only if ws too small.
// ---------------------------------------------------------------------------
template <int CLAMP>
__global__ __launch_bounds__(256) void k_follow(const int* __restrict__ subj,
                                                const int* __restrict__ rel,
                                                const int* __restrict__ obj,
                                                const float* __restrict__ srcT,
                                                const float* __restrict__ relT,
                                                float* __restrict__ dstT) {
  const size_t stride = (size_t)gridDim.x * 256;
  size_t gid = (size_t)blockIdx.x * 256 + threadIdx.x;
#pragma unroll 4
  for (int it = 0; it < 4; ++it, gid += stride) {
    int k = (int)(gid >> 4);
    int b = (int)(gid & 15);
    int s = __builtin_nontemporal_load(&subj[k]);
    int r = __builtin_nontemporal_load(&rel[k]);
    int o = __builtin_nontemporal_load(&obj[k]);
    float x = srcT[(size_t)s * NB + b];
    if (CLAMP) x = fminf(x, 1.f);
    x *= relT[r * NB + b];
    atomicAdd(&dstT[(size_t)o * NB + b], x);
  }
}

// ---------------------------------------------------------------------------
// K7: hop-attn (inlined, redundant per block) + combine.  (round-6 measured)
// ---------------------------------------------------------------------------
__global__ __launch_bounds__(256) void k_combine(const float* __restrict__ e0T,
                                                 const float* __restrict__ e1T,
                                                 const float* __restrict__ ctx_h,
                                                 const float* __restrict__ hop_w,
                                                 const float* __restrict__ hop_b,
                                                 float* __restrict__ out) {
  __shared__ float s0[256 * 17], s1[256 * 17];
  __shared__ float lg[32];
  __shared__ float ha[32];
  int tid = threadIdx.x;

  {
    int pair = tid >> 3, sub = tid & 7;
    int bb = pair >> 1, t = pair & 1;
    float acc = 0.f;
    for (int h = sub; h < NH; h += 8)
      acc = fmaf(ctx_h[((size_t)bb * 2 + t) * NH + h], hop_w[h], acc);
    for (int s = 4; s; s >>= 1) acc += __shfl_xor(acc, s, 8);
    if (sub == 0) lg[pair] = acc + hop_b[0];
  }
  __syncthreads();
  if (tid < 16) {
    float l0 = lg[tid * 2], l1 = lg[tid * 2 + 1];
    float m = fmaxf(l0, l1);
    float e0 = expf(l0 - m), e1 = expf(l1 - m);
    float s = e0 + e1;
    ha[tid * 2] = e0 / s;
    ha[tid * 2 + 1] = e1 / s;
  }
  __syncthreads();

  int e0 = blockIdx.x * 256;
#pragma unroll
  for (int j = 0; j < 16; ++j) {
    int idx = j * 256 + tid;  // (i,b)
    int i = idx >> 4, b = idx & 15;
    if (e0 + i < NE) {
      s0[i * 17 + b] = fminf(e0T[(size_t)e0 * NB + idx], 1.f);
      s1[i * 17 + b] = fminf(e1T[(size_t)e0 * NB + idx], 1.f);
    }
  }
  __syncthreads();
  if (e0 + tid < NE) {
#pragma unroll
    for (int b = 0; b < NB; ++b) {
      float a0 = ha[b * 2], a1 = ha[b * 2 + 1];
      out[(size_t)b * NE + e0 + tid] = a0 * s0[tid * 17 + b] + a1 * s1[tid * 17 + b];
    }
  }
}

// ---------------------------------------------------------------------------
extern "C" void kernel_launch(void* const* d_in, const int* in_sizes, int n_in,
                              void* d_out, int out_size, void* d_ws, size_t ws_size,
                              hipStream_t stream) {
  const float* heads = (const float*)d_in[0];
  const float* q_word_h = (const float*)d_in[1];
  const float* mask = (const float*)d_in[2];
  const int* subj = (const int*)d_in[3];
  const int* rel = (const int*)d_in[4];
  const int* obj = (const int*)d_in[5];
  const float* key_w = (const float*)d_in[6];
  const float* key_b = (const float*)d_in[7];
  const float* rel_w = (const float*)d_in[8];
  const float* rel_b = (const float*)d_in[9];
  const float* hop_w = (const float*)d_in[10];
  const float* hop_b = (const float*)d_in[11];
  const float* hw_w = (const float*)d_in[12];
  const float* hw_b = (const float*)d_in[13];

  float* ws = (float*)d_ws;
  size_t o = 0;
  float* headsT = ws + o; o += (size_t)NE * NB;
  float* e0T    = ws + o; o += (size_t)NE * NB;   // contiguous with e1T
  float* e1T    = ws + o; o += (size_t)NE * NB;
  float* h_key  = ws + o; o += (size_t)NB * NL * NH;
  float* qhopB  = ws + o; o += (size_t)NB * NL * NH;
  float* pcB    = ws + o; o += (size_t)NB * NL * NH;
  float* zbuf   = ws + o; o += (size_t)NB * NL * NH;
  float* q_dist = ws + o; o += (size_t)NB * NL * NL;
  float* att    = ws + o; o += (size_t)NB * NL;
  float* ctx_h  = ws + o; o += (size_t)NB * 2 * NH;
  float* relT   = ws + o; o += (size_t)NR * NB;
  // ---- int region (CSR) ----
  o = (o + 1) & ~(size_t)1;                       // 8B align
  int* deg    = (int*)(ws + o); o += NE;
  int* off    = (int*)(ws + o); o += NE + 1;
  int* cursor = (int*)(ws + o); o += NE;
  int* bsum   = (int*)(ws + o); o += EB_BLOCKS;
  int* bbase  = (int*)(ws + o); o += EB_BLOCKS;
  o = (o + 1) & ~(size_t)1;                       // 8B align for int2
  int2* csr   = (int2*)(ws + o); o += (size_t)NT * 2;

  const bool use_csr = ws_size >= o * sizeof(float);

  const int MM_BLOCKS = (NB * NL) / 2;                 // 256 (2 rows/block)
  const int FOLLOW_BLOCKS = (NT * 16) / (256 * 4);     // 31250 (fallback)
  const int CSR_FOLLOW_BLOCKS = NE / 16;               // 12500 (exact)

  if (use_csr) {
    // ---- CSR build (obj/subj/rel shared by both steps) ----
    hipMemsetAsync(deg, 0, (size_t)NE * sizeof(int), stream);
    k_hist<<<NT_BLOCKS, 256, 0, stream>>>(obj, deg);
    k_scan1<<<EB_BLOCKS, 256, 0, stream>>>(deg, bsum);
    k_scan2<<<1, 1024, 0, stream>>>(bsum, bbase, off);
    k_scan3<<<EB_BLOCKS, 256, 0, stream>>>(deg, bbase, off, cursor);
    k_fill<<<NT_BLOCKS, 256, 0, stream>>>(subj, rel, obj, cursor, csr);
  } else {
    hipMemsetAsync(e0T, 0, (size_t)2 * NE * NB * sizeof(float), stream);
  }
  k_transpose<<<EB_BLOCKS, 256, 0, stream>>>(heads, headsT);

  // ---- step 0 (q_hop == q_word_h) ----
  k_rowmm2<<<MM_BLOCKS, 256, 0, stream>>>(q_word_h, key_w, key_b, h_key, 0,
                                          q_word_h, key_w, key_b, h_key, 0, MM_BLOCKS);
  k_attn<<<NB, 1024, 0, stream>>>(q_word_h, h_key, mask, q_dist, att);
  k_update_rel<0><<<NB, 256, 0, stream>>>(q_word_h, q_word_h, q_dist, att, nullptr,
                                          nullptr, qhopB, pcB, ctx_h, rel_w, rel_b, relT);
  if (use_csr)
    k_follow_csr<0><<<CSR_FOLLOW_BLOCKS, 256, 0, stream>>>(off, csr, headsT, relT, e0T);
  else
    k_follow<0><<<FOLLOW_BLOCKS, 256, 0, stream>>>(subj, rel, obj, headsT, relT, e0T);

  // ---- step 1 (key-proj of qhopB and hw-proj of pcB fused in one launch) ----
  k_rowmm2<<<2 * MM_BLOCKS, 256, 0, stream>>>(qhopB, key_w, key_b, h_key, 0,
                                              pcB, hw_w, hw_b, zbuf, 1, MM_BLOCKS);
  k_attn<<<NB, 1024, 0, stream>>>(q_word_h, h_key, mask, q_dist, att);
  k_update_rel<1><<<NB, 256, 0, stream>>>(q_word_h, qhopB, q_dist, att, zbuf, pcB,
                                          nullptr, nullptr, ctx_h, rel_w, rel_b, relT);
  if (use_csr)
    k_follow_csr<1><<<CSR_FOLLOW_BLOCKS, 256, 0, stream>>>(off, csr, e0T, relT, e1T);
  else
    k_follow<1><<<FOLLOW_BLOCKS, 256, 0, stream>>>(subj, rel, obj, e0T, relT, e1T);

  // ---- epilogue (hop-attn fused into combine) ----
  k_combine<<<EB_BLOCKS, 256, 0, stream>>>(e0T, e1T, ctx_h, hop_w, hop_b, (float*)d_out);
}

// Round 8
// 559.938 us; speedup vs baseline: 1.3143x; 1.3143x over previous
//
#include <hip/hip_runtime.h>
#include <hip/hip_bf16.h>
#include <math.h>

#define NB 16       // B
#define NL 32       // L
#define NH 768      // H
#define NE 200000   // E
#define NR 512      // R
#define NT 2000000  // T
#define FEPS 1e-6f

#define EB_BLOCKS ((NE + 255) / 256)   // 782

typedef float f32x4 __attribute__((ext_vector_type(4)));

// ---------------------------------------------------------------------------
// K0: transpose heads (B,E) -> headsT (E,B), and zero e0T/e1T (fused memset).
// ---------------------------------------------------------------------------
__global__ __launch_bounds__(256) void k_transpose_zero(const float* __restrict__ heads,
                                                        float* __restrict__ headsT,
                                                        float* __restrict__ e0T,
                                                        float* __restrict__ e1T) {
  __shared__ float tile[256][17];
  int e0 = blockIdx.x * 256;
  int tid = threadIdx.x;
  if (e0 + tid < NE) {
#pragma unroll
    for (int b = 0; b < NB; ++b)
      tile[tid][b] = heads[(size_t)b * NE + e0 + tid];
  }
  // zero this block's slice of e0T/e1T: 256 entities x 16 = 4096 floats each
  {
    f32x4 z = {0.f, 0.f, 0.f, 0.f};
#pragma unroll
    for (int j = 0; j < 4; ++j) {
      int idx4 = j * 256 + tid;             // f32x4 index over 1024 = 4096/4
      size_t base = (size_t)e0 * NB + idx4 * 4;
      if (base < (size_t)NE * NB) {
        *(f32x4*)(e0T + base) = z;
        *(f32x4*)(e1T + base) = z;
      }
    }
  }
  __syncthreads();
#pragma unroll
  for (int j = 0; j < 16; ++j) {
    int idx = j * 256 + tid;      // 0..4095 over (i,b)
    int i = idx >> 4, b = idx & 15;
    if (e0 + i < NE) headsT[(size_t)(e0 + i) * NB + b] = tile[i][b];
  }
}

// ---------------------------------------------------------------------------
// K1: dual row-MM (measured).  Blocks < nblk0: Y0 = act0(X0@W0+b0); else
// Y1 = act1(X1@W1+b1).  2 rows/block, 256 threads, thread owns 3 h-columns.
// ---------------------------------------------------------------------------
__global__ __launch_bounds__(256) void k_rowmm2(const float* __restrict__ X0,
                                                const float* __restrict__ W0,
                                                const float* __restrict__ b0,
                                                float* __restrict__ Y0, int act0,
                                                const float* __restrict__ X1,
                                                const float* __restrict__ W1,
                                                const float* __restrict__ b1,
                                                float* __restrict__ Y1, int act1,
                                                int nblk0) {
  const float* X; const float* W; const float* bias; float* Y; int act, row0;
  int blk = blockIdx.x;
  if (blk < nblk0) { X = X0; W = W0; bias = b0; Y = Y0; act = act0; row0 = blk * 2; }
  else            { X = X1; W = W1; bias = b1; Y = Y1; act = act1; row0 = (blk - nblk0) * 2; }

  __shared__ float xs[2][NH];
  int tid = threadIdx.x;
  for (int r = 0; r < 2; ++r)
    for (int k = tid; k < NH; k += 256)
      xs[r][k] = X[(size_t)(row0 + r) * NH + k];
  __syncthreads();

  float acc[2][3] = {};
  for (int k = 0; k < NH; ++k) {
    float w0 = W[(size_t)k * NH + tid];
    float w1 = W[(size_t)k * NH + tid + 256];
    float w2 = W[(size_t)k * NH + tid + 512];
#pragma unroll
    for (int r = 0; r < 2; ++r) {
      float x = xs[r][k];
      acc[r][0] = fmaf(x, w0, acc[r][0]);
      acc[r][1] = fmaf(x, w1, acc[r][1]);
      acc[r][2] = fmaf(x, w2, acc[r][2]);
    }
  }
  float bb0 = bias[tid], bb1 = bias[tid + 256], bb2 = bias[tid + 512];
#pragma unroll
  for (int r = 0; r < 2; ++r) {
    size_t base = (size_t)(row0 + r) * NH;
    float y0 = acc[r][0] + bb0, y1 = acc[r][1] + bb1, y2 = acc[r][2] + bb2;
    if (act == 1) {
      y0 = 1.f / (1.f + expf(-y0));
      y1 = 1.f / (1.f + expf(-y1));
      y2 = 1.f / (1.f + expf(-y2));
    }
    Y[base + tid] = y0;
    Y[base + tid + 256] = y1;
    Y[base + tid + 512] = y2;
  }
}

// ---------------------------------------------------------------------------
// K2: fused attn + update + rel per b.  One block per b, 1024 threads.
// attn: q_logits = qwh @ h_key^T; softmax*mask renorm -> qd (LDS only);
// colsum -> att (LDS only).  update: hop_ctx = qd @ qhop; qn; ctx = att^T@qn;
// rel: relT[r*16+b] = sigmoid(ctx . rel_w[:,r] + rel_b[r]).
// q_dist / att never touch global memory.
// LDS: qs_full 96KB + hks 16.5KB + qd 4.2KB + ctx_s 3KB + as ~= 122KB.
// ---------------------------------------------------------------------------
template <int STEP>
__global__ __launch_bounds__(1024) void k_attn_update(const float* __restrict__ qwh,
                                                      const float* __restrict__ hkey,
                                                      const float* __restrict__ mask,
                                                      const float* __restrict__ qhop_old,
                                                      const float* __restrict__ zbuf,
                                                      const float* __restrict__ pc_old,
                                                      float* __restrict__ qhop_new,
                                                      float* __restrict__ pc_new,
                                                      float* __restrict__ ctx_h,
                                                      const float* __restrict__ rel_w,
                                                      const float* __restrict__ rel_b,
                                                      float* __restrict__ relT) {
  int b = blockIdx.x;
  int tid = threadIdx.x;
  __shared__ float qs_full[NL * NH];     // qwh[b] rows, stride 768
  __shared__ float hks[32 * 129];        // h_key k-tile, stride 129
  __shared__ float qd[32 * 33];
  __shared__ float ctx_s[NH];
  __shared__ float as[NL];

  // stage qwh[b] (32x768) via float4: 6144 f4 / 1024 thr = 6 each
#pragma unroll
  for (int it = 0; it < 6; ++it) {
    int idx4 = it * 1024 + tid;
    f32x4 v = *(const f32x4*)(qwh + (size_t)b * NL * NH + idx4 * 4);
    *(f32x4*)(qs_full + idx4 * 4) = v;
  }
  __syncthreads();

  // ---- attention: acc(i,j) over 6 k-tiles of 128 ----
  int i = tid >> 5, j = tid & 31;
  float acc = 0.f;
  for (int k0 = 0; k0 < NH; k0 += 128) {
    {
      int jj = tid >> 5;      // row
      int kk4 = tid & 31;     // f4 within tile
      f32x4 hv = *(const f32x4*)(hkey + ((size_t)b * NL + jj) * NH + k0 + kk4 * 4);
      int base = jj * 129 + kk4 * 4;
      hks[base] = hv.x; hks[base + 1] = hv.y; hks[base + 2] = hv.z; hks[base + 3] = hv.w;
    }
    __syncthreads();
#pragma unroll 8
    for (int kk = 0; kk < 128; ++kk)
      acc = fmaf(qs_full[i * NH + k0 + kk], hks[j * 129 + kk], acc);
    __syncthreads();
  }

  // softmax over j within aligned 32-lane groups
  float m = acc;
  for (int s = 16; s; s >>= 1) m = fmaxf(m, __shfl_xor(m, s, 32));
  float ex = expf(acc - m);
  float sum = ex;
  for (int s = 16; s; s >>= 1) sum += __shfl_xor(sum, s, 32);
  float p = ex / sum;
  p *= mask[b * NL + j];
  float s2 = p;
  for (int s = 16; s; s >>= 1) s2 += __shfl_xor(s2, s, 32);
  p = p / (s2 + FEPS);
  qd[i * 33 + j] = p;
  __syncthreads();

  // colsum -> word attention (LDS only)
  if (tid < 32) {
    int jj = tid;
    float c = 0.f;
    for (int ii = 0; ii < 32; ++ii) c += qd[ii * 33 + jj];
    float mm = c;
    for (int s = 16; s; s >>= 1) mm = fmaxf(mm, __shfl_xor(mm, s, 32));
    float e2 = expf(c - mm);
    float ss = e2;
    for (int s = 16; s; s >>= 1) ss += __shfl_xor(ss, s, 32);
    float a = e2 / ss;
    a *= mask[b * NL + jj];
    float s3 = a;
    for (int s = 16; s; s >>= 1) s3 += __shfl_xor(s3, s, 32);
    as[jj] = a / (s3 + FEPS);
  }
  __syncthreads();

  // ---- update: threads 0..767 each own one h ----
  if (tid < NH) {
    int h = tid;
    float qh[NL];
#pragma unroll
    for (int jj = 0; jj < NL; ++jj) {
      if (STEP == 0)
        qh[jj] = qs_full[jj * NH + h];                       // qhop==qwh, LDS
      else
        qh[jj] = qhop_old[((size_t)b * NL + jj) * NH + h];   // qhopB, coalesced
    }
    float c = 0.f;
    for (int l = 0; l < NL; ++l) {
      float hop = 0.f;
#pragma unroll
      for (int jj = 0; jj < NL; ++jj)
        hop = fmaf(qd[l * 33 + jj], qh[jj], hop);
      size_t base = ((size_t)b * NL + l) * NH + h;
      float qn;
      if (STEP == 0) {
        qn = qs_full[l * NH + h] + hop;
        qhop_new[base] = qn;
        pc_new[base] = hop;
      } else {
        float t = zbuf[base] * pc_old[base];
        qn = qs_full[l * NH + h] + hop + t;
      }
      c = fmaf(as[l], qn, c);
    }
    ctx_h[((size_t)b * 2 + STEP) * NH + h] = c;
    ctx_s[h] = c;
  }
  __syncthreads();

  // ---- rel projection: threads 0..511 each own one r ----
  if (tid < NR) {
    int r = tid;
    float a = rel_b[r];
    for (int h = 0; h < NH; ++h)
      a = fmaf(ctx_s[h], rel_w[(size_t)h * NR + r], a);
    relT[r * NB + b] = 1.f / (1.f + expf(-a));
  }
}

// ---------------------------------------------------------------------------
// K5: follow (measured round-1/6 form, ~113us). One (edge,b) per lane-iter;
// 16-lane groups share index loads; one 64B line per gather/relT/scatter.
// Grid-stride x4 unrolled; nontemporal index loads; CLAMP fuses z_norm.
// ---------------------------------------------------------------------------
template <int CLAMP>
__global__ __launch_bounds__(256) void k_follow(const int* __restrict__ subj,
                                                const int* __restrict__ rel,
                                                const int* __restrict__ obj,
                                                const float* __restrict__ srcT,
                                                const float* __restrict__ relT,
                                                float* __restrict__ dstT) {
  const size_t stride = (size_t)gridDim.x * 256;
  size_t gid = (size_t)blockIdx.x * 256 + threadIdx.x;
#pragma unroll 4
  for (int it = 0; it < 4; ++it, gid += stride) {
    int k = (int)(gid >> 4);
    int b = (int)(gid & 15);
    int s = __builtin_nontemporal_load(&subj[k]);
    int r = __builtin_nontemporal_load(&rel[k]);
    int o = __builtin_nontemporal_load(&obj[k]);
    float x = srcT[(size_t)s * NB + b];
    if (CLAMP) x = fminf(x, 1.f);
    x *= relT[r * NB + b];
    atomicAdd(&dstT[(size_t)o * NB + b], x);
  }
}

// ---------------------------------------------------------------------------
// K7: hop-attn (inlined, redundant per block) + combine.  (measured)
// ---------------------------------------------------------------------------
__global__ __launch_bounds__(256) void k_combine(const float* __restrict__ e0T,
                                                 const float* __restrict__ e1T,
                                                 const float* __restrict__ ctx_h,
                                                 const float* __restrict__ hop_w,
                                                 const float* __restrict__ hop_b,
                                                 float* __restrict__ out) {
  __shared__ float s0[256 * 17], s1[256 * 17];
  __shared__ float lg[32];
  __shared__ float ha[32];
  int tid = threadIdx.x;

  {
    int pair = tid >> 3, sub = tid & 7;
    int bb = pair >> 1, t = pair & 1;
    float acc = 0.f;
    for (int h = sub; h < NH; h += 8)
      acc = fmaf(ctx_h[((size_t)bb * 2 + t) * NH + h], hop_w[h], acc);
    for (int s = 4; s; s >>= 1) acc += __shfl_xor(acc, s, 8);
    if (sub == 0) lg[pair] = acc + hop_b[0];
  }
  __syncthreads();
  if (tid < 16) {
    float l0 = lg[tid * 2], l1 = lg[tid * 2 + 1];
    float m = fmaxf(l0, l1);
    float e0 = expf(l0 - m), e1 = expf(l1 - m);
    float s = e0 + e1;
    ha[tid * 2] = e0 / s;
    ha[tid * 2 + 1] = e1 / s;
  }
  __syncthreads();

  int e0 = blockIdx.x * 256;
#pragma unroll
  for (int j = 0; j < 16; ++j) {
    int idx = j * 256 + tid;  // (i,b)
    int i = idx >> 4, b = idx & 15;
    if (e0 + i < NE) {
      s0[i * 17 + b] = fminf(e0T[(size_t)e0 * NB + idx], 1.f);
      s1[i * 17 + b] = fminf(e1T[(size_t)e0 * NB + idx], 1.f);
    }
  }
  __syncthreads();
  if (e0 + tid < NE) {
#pragma unroll
    for (int b = 0; b < NB; ++b) {
      float a0 = ha[b * 2], a1 = ha[b * 2 + 1];
      out[(size_t)b * NE + e0 + tid] = a0 * s0[tid * 17 + b] + a1 * s1[tid * 17 + b];
    }
  }
}

// ---------------------------------------------------------------------------
extern "C" void kernel_launch(void* const* d_in, const int* in_sizes, int n_in,
                              void* d_out, int out_size, void* d_ws, size_t ws_size,
                              hipStream_t stream) {
  const float* heads = (const float*)d_in[0];
  const float* q_word_h = (const float*)d_in[1];
  const float* mask = (const float*)d_in[2];
  const int* subj = (const int*)d_in[3];
  const int* rel = (const int*)d_in[4];
  const int* obj = (const int*)d_in[5];
  const float* key_w = (const float*)d_in[6];
  const float* key_b = (const float*)d_in[7];
  const float* rel_w = (const float*)d_in[8];
  const float* rel_b = (const float*)d_in[9];
  const float* hop_w = (const float*)d_in[10];
  const float* hop_b = (const float*)d_in[11];
  const float* hw_w = (const float*)d_in[12];
  const float* hw_b = (const float*)d_in[13];

  float* ws = (float*)d_ws;
  size_t o = 0;
  float* headsT = ws + o; o += (size_t)NE * NB;
  float* e0T    = ws + o; o += (size_t)NE * NB;
  float* e1T    = ws + o; o += (size_t)NE * NB;
  float* h_key  = ws + o; o += (size_t)NB * NL * NH;
  float* qhopB  = ws + o; o += (size_t)NB * NL * NH;
  float* pcB    = ws + o; o += (size_t)NB * NL * NH;
  float* zbuf   = ws + o; o += (size_t)NB * NL * NH;
  float* ctx_h  = ws + o; o += (size_t)NB * 2 * NH;
  float* relT   = ws + o; o += (size_t)NR * NB;

  const int MM_BLOCKS = (NB * NL) / 2;                 // 256 (2 rows/block)
  const int FOLLOW_BLOCKS = (NT * 16) / (256 * 4);     // 31250 (exact)

  // transpose + fused zeroing of e0T/e1T
  k_transpose_zero<<<EB_BLOCKS, 256, 0, stream>>>(heads, headsT, e0T, e1T);

  // ---- step 0 (q_hop == q_word_h) ----
  k_rowmm2<<<MM_BLOCKS, 256, 0, stream>>>(q_word_h, key_w, key_b, h_key, 0,
                                          q_word_h, key_w, key_b, h_key, 0, MM_BLOCKS);
  k_attn_update<0><<<NB, 1024, 0, stream>>>(q_word_h, h_key, mask, q_word_h,
                                            nullptr, nullptr, qhopB, pcB, ctx_h,
                                            rel_w, rel_b, relT);
  k_follow<0><<<FOLLOW_BLOCKS, 256, 0, stream>>>(subj, rel, obj, headsT, relT, e0T);

  // ---- step 1 (key-proj of qhopB and hw-proj of pcB in one launch) ----
  k_rowmm2<<<2 * MM_BLOCKS, 256, 0, stream>>>(qhopB, key_w, key_b, h_key, 0,
                                              pcB, hw_w, hw_b, zbuf, 1, MM_BLOCKS);
  k_attn_update<1><<<NB, 1024, 0, stream>>>(q_word_h, h_key, mask, qhopB,
                                            zbuf, pcB, nullptr, nullptr, ctx_h,
                                            rel_w, rel_b, relT);
  k_follow<1><<<FOLLOW_BLOCKS, 256, 0, stream>>>(subj, rel, obj, e0T, relT, e1T);

  // ---- epilogue ----
  k_combine<<<EB_BLOCKS, 256, 0, stream>>>(e0T, e1T, ctx_h, hop_w, hop_b, (float*)d_out);
}

// Round 10
// 547.274 us; speedup vs baseline: 1.3447x; 1.0231x over previous
//
#include <hip/hip_runtime.h>
#include <hip/hip_bf16.h>
#include <math.h>

#define NB 16       // B
#define NL 32       // L
#define NH 768      // H
#define NE 200000   // E
#define NR 512      // R
#define NT 2000000  // T
#define FEPS 1e-6f

#define EB_BLOCKS ((NE + 255) / 256)   // 782
#define FOLLOW_BLOCKS 31250            // (NT*16)/(256*4), exact

typedef float f32x4 __attribute__((ext_vector_type(4)));

// ---------------------------------------------------------------------------
// Shared device body: one 256-thread group computes 2 rows of
// Y = act(X @ W + bias).  Exact measured k_rowmm2 inner form.
// ---------------------------------------------------------------------------
__device__ __forceinline__ void rowmm_body(const float* __restrict__ X,
                                           const float* __restrict__ W,
                                           const float* __restrict__ bias,
                                           float* __restrict__ Y, int act, int row0,
                                           float* __restrict__ xs /* 2*NH floats */) {
  int tid = threadIdx.x;
  for (int r = 0; r < 2; ++r)
    for (int k = tid; k < NH; k += 256)
      xs[r * NH + k] = X[(size_t)(row0 + r) * NH + k];
  __syncthreads();

  float acc[2][3] = {};
  for (int k = 0; k < NH; ++k) {
    float w0 = W[(size_t)k * NH + tid];
    float w1 = W[(size_t)k * NH + tid + 256];
    float w2 = W[(size_t)k * NH + tid + 512];
#pragma unroll
    for (int r = 0; r < 2; ++r) {
      float x = xs[r * NH + k];
      acc[r][0] = fmaf(x, w0, acc[r][0]);
      acc[r][1] = fmaf(x, w1, acc[r][1]);
      acc[r][2] = fmaf(x, w2, acc[r][2]);
    }
  }
  float bb0 = bias[tid], bb1 = bias[tid + 256], bb2 = bias[tid + 512];
#pragma unroll
  for (int r = 0; r < 2; ++r) {
    size_t base = (size_t)(row0 + r) * NH;
    float y0 = acc[r][0] + bb0, y1 = acc[r][1] + bb1, y2 = acc[r][2] + bb2;
    if (act == 1) {
      y0 = 1.f / (1.f + expf(-y0));
      y1 = 1.f / (1.f + expf(-y1));
      y2 = 1.f / (1.f + expf(-y2));
    }
    Y[base + tid] = y0;
    Y[base + tid + 256] = y1;
    Y[base + tid + 512] = y2;
  }
}

// ---------------------------------------------------------------------------
// K-PRE: blocks 0..781 transpose heads -> headsT and zero e0T/e1T;
// blocks 782..1037 compute step-0 h_key = qwh @ key_w + key_b (rowmm).
// Independent work fused into one dispatch (block-uniform branch).
// ---------------------------------------------------------------------------
__global__ __launch_bounds__(256) void k_pre(const float* __restrict__ heads,
                                             float* __restrict__ headsT,
                                             float* __restrict__ e0T,
                                             float* __restrict__ e1T,
                                             const float* __restrict__ qwh,
                                             const float* __restrict__ key_w,
                                             const float* __restrict__ key_b,
                                             float* __restrict__ h_key) {
  __shared__ float sm[256 * 17];   // transpose tile; rowmm uses first 2*NH
  int blk = blockIdx.x;
  int tid = threadIdx.x;
  if (blk < EB_BLOCKS) {
    float (*tile)[17] = (float (*)[17])sm;
    int e0 = blk * 256;
    if (e0 + tid < NE) {
#pragma unroll
      for (int b = 0; b < NB; ++b)
        tile[tid][b] = heads[(size_t)b * NE + e0 + tid];
    }
    // zero this block's slice of e0T/e1T (fused memset)
    {
      f32x4 z = {0.f, 0.f, 0.f, 0.f};
#pragma unroll
      for (int j = 0; j < 4; ++j) {
        int idx4 = j * 256 + tid;
        size_t base = (size_t)e0 * NB + idx4 * 4;
        if (base < (size_t)NE * NB) {
          *(f32x4*)(e0T + base) = z;
          *(f32x4*)(e1T + base) = z;
        }
      }
    }
    __syncthreads();
#pragma unroll
    for (int j = 0; j < 16; ++j) {
      int idx = j * 256 + tid;
      int i = idx >> 4, b = idx & 15;
      if (e0 + i < NE) headsT[(size_t)(e0 + i) * NB + b] = tile[i][b];
    }
  } else {
    rowmm_body(qwh, key_w, key_b, h_key, 0, (blk - EB_BLOCKS) * 2, sm);
  }
}

// ---------------------------------------------------------------------------
// K2: fused attn + update + rel per b (measured round-8 form).
// One block per b, 1024 threads; q_dist/att stay in LDS.
// ---------------------------------------------------------------------------
template <int STEP>
__global__ __launch_bounds__(1024) void k_attn_update(const float* __restrict__ qwh,
                                                      const float* __restrict__ hkey,
                                                      const float* __restrict__ mask,
                                                      const float* __restrict__ qhop_old,
                                                      const float* __restrict__ zbuf,
                                                      const float* __restrict__ pc_old,
                                                      float* __restrict__ qhop_new,
                                                      float* __restrict__ pc_new,
                                                      float* __restrict__ ctx_h,
                                                      const float* __restrict__ rel_w,
                                                      const float* __restrict__ rel_b,
                                                      float* __restrict__ relT) {
  int b = blockIdx.x;
  int tid = threadIdx.x;
  __shared__ float qs_full[NL * NH];     // qwh[b] rows, stride 768
  __shared__ float hks[32 * 129];        // h_key k-tile, stride 129
  __shared__ float qd[32 * 33];
  __shared__ float ctx_s[NH];
  __shared__ float as[NL];

#pragma unroll
  for (int it = 0; it < 6; ++it) {
    int idx4 = it * 1024 + tid;
    f32x4 v = *(const f32x4*)(qwh + (size_t)b * NL * NH + idx4 * 4);
    *(f32x4*)(qs_full + idx4 * 4) = v;
  }
  __syncthreads();

  int i = tid >> 5, j = tid & 31;
  float acc = 0.f;
  for (int k0 = 0; k0 < NH; k0 += 128) {
    {
      int jj = tid >> 5;
      int kk4 = tid & 31;
      f32x4 hv = *(const f32x4*)(hkey + ((size_t)b * NL + jj) * NH + k0 + kk4 * 4);
      int base = jj * 129 + kk4 * 4;
      hks[base] = hv.x; hks[base + 1] = hv.y; hks[base + 2] = hv.z; hks[base + 3] = hv.w;
    }
    __syncthreads();
#pragma unroll 8
    for (int kk = 0; kk < 128; ++kk)
      acc = fmaf(qs_full[i * NH + k0 + kk], hks[j * 129 + kk], acc);
    __syncthreads();
  }

  float m = acc;
  for (int s = 16; s; s >>= 1) m = fmaxf(m, __shfl_xor(m, s, 32));
  float ex = expf(acc - m);
  float sum = ex;
  for (int s = 16; s; s >>= 1) sum += __shfl_xor(sum, s, 32);
  float p = ex / sum;
  p *= mask[b * NL + j];
  float s2 = p;
  for (int s = 16; s; s >>= 1) s2 += __shfl_xor(s2, s, 32);
  p = p / (s2 + FEPS);
  qd[i * 33 + j] = p;
  __syncthreads();

  if (tid < 32) {
    int jj = tid;
    float c = 0.f;
    for (int ii = 0; ii < 32; ++ii) c += qd[ii * 33 + jj];
    float mm = c;
    for (int s = 16; s; s >>= 1) mm = fmaxf(mm, __shfl_xor(mm, s, 32));
    float e2 = expf(c - mm);
    float ss = e2;
    for (int s = 16; s; s >>= 1) ss += __shfl_xor(ss, s, 32);
    float a = e2 / ss;
    a *= mask[b * NL + jj];
    float s3 = a;
    for (int s = 16; s; s >>= 1) s3 += __shfl_xor(s3, s, 32);
    as[jj] = a / (s3 + FEPS);
  }
  __syncthreads();

  if (tid < NH) {
    int h = tid;
    float qh[NL];
#pragma unroll
    for (int jj = 0; jj < NL; ++jj) {
      if (STEP == 0)
        qh[jj] = qs_full[jj * NH + h];
      else
        qh[jj] = qhop_old[((size_t)b * NL + jj) * NH + h];
    }
    float c = 0.f;
    for (int l = 0; l < NL; ++l) {
      float hop = 0.f;
#pragma unroll
      for (int jj = 0; jj < NL; ++jj)
        hop = fmaf(qd[l * 33 + jj], qh[jj], hop);
      size_t base = ((size_t)b * NL + l) * NH + h;
      float qn;
      if (STEP == 0) {
        qn = qs_full[l * NH + h] + hop;
        qhop_new[base] = qn;
        pc_new[base] = hop;
      } else {
        float t = zbuf[base] * pc_old[base];
        qn = qs_full[l * NH + h] + hop + t;
      }
      c = fmaf(as[l], qn, c);
    }
    ctx_h[((size_t)b * 2 + STEP) * NH + h] = c;
    ctx_s[h] = c;
  }
  __syncthreads();

  if (tid < NR) {
    int r = tid;
    float a = rel_b[r];
    for (int h = 0; h < NH; ++h)
      a = fmaf(ctx_s[h], rel_w[(size_t)h * NR + r], a);
    relT[r * NB + b] = 1.f / (1.f + expf(-a));
  }
}

// ---------------------------------------------------------------------------
// K-FOLLOW-MM: blocks 0..255 rowmm step-1 key-proj (qhopB -> h_key);
// blocks 256..511 rowmm hw-proj (pcB -> zbuf, sigmoid); blocks 512.. follow0.
// rowmm1 depends only on attn_update0 outputs (not e0T), so it hides under
// follow0's ~113us.  Follow part: exact measured form, stride hardcoded.
// ---------------------------------------------------------------------------
__global__ __launch_bounds__(256) void k_follow_mm(const float* __restrict__ qhopB,
                                                   const float* __restrict__ key_w,
                                                   const float* __restrict__ key_b,
                                                   float* __restrict__ h_key,
                                                   const float* __restrict__ pcB,
                                                   const float* __restrict__ hw_w,
                                                   const float* __restrict__ hw_b,
                                                   float* __restrict__ zbuf,
                                                   const int* __restrict__ subj,
                                                   const int* __restrict__ rel,
                                                   const int* __restrict__ obj,
                                                   const float* __restrict__ headsT,
                                                   const float* __restrict__ relT,
                                                   float* __restrict__ e0T) {
  __shared__ float xs[2 * NH];
  int blk = blockIdx.x;
  if (blk < 256) {
    rowmm_body(qhopB, key_w, key_b, h_key, 0, blk * 2, xs);
    return;
  }
  if (blk < 512) {
    rowmm_body(pcB, hw_w, hw_b, zbuf, 1, (blk - 256) * 2, xs);
    return;
  }
  // follow0 (CLAMP=0): heads values already in [0,1)
  const size_t stride = (size_t)FOLLOW_BLOCKS * 256;   // 8,000,000
  size_t gid = (size_t)(blk - 512) * 256 + threadIdx.x;
#pragma unroll 4
  for (int it = 0; it < 4; ++it, gid += stride) {
    int k = (int)(gid >> 4);
    int b = (int)(gid & 15);
    int s = __builtin_nontemporal_load(&subj[k]);
    int r = __builtin_nontemporal_load(&rel[k]);
    int o = __builtin_nontemporal_load(&obj[k]);
    float x = headsT[(size_t)s * NB + b];
    x *= relT[r * NB + b];
    atomicAdd(&e0T[(size_t)o * NB + b], x);
  }
}

// ---------------------------------------------------------------------------
// K5: follow step 1 (measured form, CLAMP fuses z_norm: min(x,1)).
// ---------------------------------------------------------------------------
template <int CLAMP>
__global__ __launch_bounds__(256) void k_follow(const int* __restrict__ subj,
                                                const int* __restrict__ rel,
                                                const int* __restrict__ obj,
                                                const float* __restrict__ srcT,
                                                const float* __restrict__ relT,
                                                float* __restrict__ dstT) {
  const size_t stride = (size_t)gridDim.x * 256;
  size_t gid = (size_t)blockIdx.x * 256 + threadIdx.x;
#pragma unroll 4
  for (int it = 0; it < 4; ++it, gid += stride) {
    int k = (int)(gid >> 4);
    int b = (int)(gid & 15);
    int s = __builtin_nontemporal_load(&subj[k]);
    int r = __builtin_nontemporal_load(&rel[k]);
    int o = __builtin_nontemporal_load(&obj[k]);
    float x = srcT[(size_t)s * NB + b];
    if (CLAMP) x = fminf(x, 1.f);
    x *= relT[r * NB + b];
    atomicAdd(&dstT[(size_t)o * NB + b], x);
  }
}

// ---------------------------------------------------------------------------
// K7: hop-attn + combine (measured form).
// ---------------------------------------------------------------------------
__global__ __launch_bounds__(256) void k_combine(const float* __restrict__ e0T,
                                                 const float* __restrict__ e1T,
                                                 const float* __restrict__ ctx_h,
                                                 const float* __restrict__ hop_w,
                                                 const float* __restrict__ hop_b,
                                                 float* __restrict__ out) {
  __shared__ float s0[256 * 17], s1[256 * 17];
  __shared__ float lg[32];
  __shared__ float ha[32];
  int tid = threadIdx.x;

  {
    int pair = tid >> 3, sub = tid & 7;
    int bb = pair >> 1, t = pair & 1;
    float acc = 0.f;
    for (int h = sub; h < NH; h += 8)
      acc = fmaf(ctx_h[((size_t)bb * 2 + t) * NH + h], hop_w[h], acc);
    for (int s = 4; s; s >>= 1) acc += __shfl_xor(acc, s, 8);
    if (sub == 0) lg[pair] = acc + hop_b[0];
  }
  __syncthreads();
  if (tid < 16) {
    float l0 = lg[tid * 2], l1 = lg[tid * 2 + 1];
    float m = fmaxf(l0, l1);
    float e0 = expf(l0 - m), e1 = expf(l1 - m);
    float s = e0 + e1;
    ha[tid * 2] = e0 / s;
    ha[tid * 2 + 1] = e1 / s;
  }
  __syncthreads();

  int e0 = blockIdx.x * 256;
#pragma unroll
  for (int j = 0; j < 16; ++j) {
    int idx = j * 256 + tid;
    int i = idx >> 4, b = idx & 15;
    if (e0 + i < NE) {
      s0[i * 17 + b] = fminf(e0T[(size_t)e0 * NB + idx], 1.f);
      s1[i * 17 + b] = fminf(e1T[(size_t)e0 * NB + idx], 1.f);
    }
  }
  __syncthreads();
  if (e0 + tid < NE) {
#pragma unroll
    for (int b = 0; b < NB; ++b) {
      float a0 = ha[b * 2], a1 = ha[b * 2 + 1];
      out[(size_t)b * NE + e0 + tid] = a0 * s0[tid * 17 + b] + a1 * s1[tid * 17 + b];
    }
  }
}

// ---------------------------------------------------------------------------
extern "C" void kernel_launch(void* const* d_in, const int* in_sizes, int n_in,
                              void* d_out, int out_size, void* d_ws, size_t ws_size,
                              hipStream_t stream) {
  const float* heads = (const float*)d_in[0];
  const float* q_word_h = (const float*)d_in[1];
  const float* mask = (const float*)d_in[2];
  const int* subj = (const int*)d_in[3];
  const int* rel = (const int*)d_in[4];
  const int* obj = (const int*)d_in[5];
  const float* key_w = (const float*)d_in[6];
  const float* key_b = (const float*)d_in[7];
  const float* rel_w = (const float*)d_in[8];
  const float* rel_b = (const float*)d_in[9];
  const float* hop_w = (const float*)d_in[10];
  const float* hop_b = (const float*)d_in[11];
  const float* hw_w = (const float*)d_in[12];
  const float* hw_b = (const float*)d_in[13];

  float* ws = (float*)d_ws;
  size_t o = 0;
  float* headsT = ws + o; o += (size_t)NE * NB;
  float* e0T    = ws + o; o += (size_t)NE * NB;
  float* e1T    = ws + o; o += (size_t)NE * NB;
  float* h_key  = ws + o; o += (size_t)NB * NL * NH;
  float* qhopB  = ws + o; o += (size_t)NB * NL * NH;
  float* pcB    = ws + o; o += (size_t)NB * NL * NH;
  float* zbuf   = ws + o; o += (size_t)NB * NL * NH;
  float* ctx_h  = ws + o; o += (size_t)NB * 2 * NH;
  float* relT   = ws + o; o += (size_t)NR * NB;

  // ---- node 1: transpose+zero (782 blocks) || step-0 rowmm (256 blocks) ----
  k_pre<<<EB_BLOCKS + 256, 256, 0, stream>>>(heads, headsT, e0T, e1T,
                                             q_word_h, key_w, key_b, h_key);

  // ---- node 2: step-0 attn+update+rel ----
  k_attn_update<0><<<NB, 1024, 0, stream>>>(q_word_h, h_key, mask, q_word_h,
                                            nullptr, nullptr, qhopB, pcB, ctx_h,
                                            rel_w, rel_b, relT);

  // ---- node 3: follow0 (31250 blocks) || step-1 dual rowmm (512 blocks) ----
  k_follow_mm<<<512 + FOLLOW_BLOCKS, 256, 0, stream>>>(qhopB, key_w, key_b, h_key,
                                                       pcB, hw_w, hw_b, zbuf,
                                                       subj, rel, obj,
                                                       headsT, relT, e0T);

  // ---- node 4: step-1 attn+update+rel ----
  k_attn_update<1><<<NB, 1024, 0, stream>>>(q_word_h, h_key, mask, qhopB,
                                            zbuf, pcB, nullptr, nullptr, ctx_h,
                                            rel_w, rel_b, relT);

  // ---- node 5: follow1 ----
  k_follow<1><<<FOLLOW_BLOCKS, 256, 0, stream>>>(subj, rel, obj, e0T, relT, e1T);

  // ---- node 6: hop-attn + combine ----
  k_combine<<<EB_BLOCKS, 256, 0, stream>>>(e0T, e1T, ctx_h, hop_w, hop_b, (float*)d_out);
}